// Round 4
// baseline (1651.615 us; speedup 1.0000x reference)
//
#include <hip/hip_runtime.h>
#include <stdint.h>

// ---------------------------------------------------------------------------
// T3KAN pipeline on MI355X. ALL inputs and the output are float32.
//
//  0. split_kernel    : fp32 -> (hi,lo) bf16 for x, Wq, Wk, Wv, Wo
//  1. eta_kernel      : lr = sigmoid(x . lrW_h + b_h)/64 * gs[m]  -> eta fp32
//  2. qkv_rope_kernel : QKV = x @ W^T, 3-pass split-bf16 MFMA, m97-style
//                       128x128 LDS-staged tiles (global_load_lds w=16) + RoPE
//  3. scan_kernel     : 128-step TTT scan (sparse uniform-knot B-spline)
//  4. ln_kernel       : final LayerNorm -> (hi,lo) bf16
//  5. out_gemm_kernel : ln @ Wo^T, same m97-style tiled split GEMM -> fp32
// ---------------------------------------------------------------------------

typedef unsigned short ushort_t;
typedef short bf16x8 __attribute__((ext_vector_type(8)));
typedef float f32x4 __attribute__((ext_vector_type(4)));

#define GLOAD_LDS16(gsrc, ldst)                                                \
    __builtin_amdgcn_global_load_lds(                                          \
        (const __attribute__((address_space(1))) void*)(gsrc),                 \
        (__attribute__((address_space(3))) void*)(ldst), 16, 0, 0)

__device__ __forceinline__ float bf2f(ushort_t u) {
    union { uint32_t i; float f; } v; v.i = ((uint32_t)u) << 16; return v.f;
}
__device__ __forceinline__ ushort_t f2bf(float f) {   // RNE fp32->bf16
    union { float f; uint32_t i; } v; v.f = f;
    uint32_t r = v.i + 0x7FFFu + ((v.i >> 16) & 1u);
    return (ushort_t)(r >> 16);
}
__device__ __forceinline__ float silu(float x) { return x / (1.0f + expf(-x)); }

__device__ __forceinline__ void wave_reduce2(float& a, float& b) {
#pragma unroll
    for (int off = 32; off > 0; off >>= 1) {
        a += __shfl_xor(a, off, 64);
        b += __shfl_xor(b, off, 64);
    }
}

// ---------------------------------------------------------------------------
// Sparse degree-3 B-spline on UNIFORM knots linspace(-1,1,15), delta=1/7.
// 4 nonzero basis values; j-slot 11 is a dummy zero. Zero divides.
// ---------------------------------------------------------------------------
struct Bas4 { float n[4]; int j[4]; };
__device__ __forceinline__ Bas4 bspline4(float x) {
    const float DELTA = 0.14285714285714285f;  // 1/7
    const float xp1 = x + 1.0f;
    const float fi = floorf(xp1 * 7.0f);
    const bool valid = (fi >= 0.0f) && (fi <= 13.0f);
    const float fic = valid ? fi : 0.0f;
    const float left1  = xp1 - fic * DELTA;
    const float left2  = xp1 - (fic - 1.0f) * DELTA;
    const float left3  = xp1 - (fic - 2.0f) * DELTA;
    const float right1 = (fic + 1.0f) * DELTA - xp1;
    const float right2 = (fic + 2.0f) * DELTA - xp1;
    const float right3 = (fic + 3.0f) * DELTA - xp1;
    float N0, N1, N2, N3, saved, temp;
    temp = 7.0f;
    N0 = right1 * temp;
    N1 = left1 * temp;
    temp = N0 * 3.5f;
    N0 = right1 * temp; saved = left2 * temp;
    temp = N1 * 3.5f;
    N1 = fmaf(right2, temp, saved);
    N2 = left1 * temp;
    const float inv3 = 2.3333333333333335f;
    temp = N0 * inv3;
    N0 = right1 * temp; saved = left3 * temp;
    temp = N1 * inv3;
    N1 = fmaf(right2, temp, saved); saved = left2 * temp;
    temp = N2 * inv3;
    N2 = fmaf(right3, temp, saved);
    N3 = left1 * temp;

    Bas4 r;
    const int i = (int)fic;
    const float nv[4] = {N0, N1, N2, N3};
#pragma unroll
    for (int t = 0; t < 4; ++t) {
        const int j = i - 3 + t;
        const bool ok = valid && (j >= 0) && (j <= 10);
        r.n[t] = ok ? nv[t] : 0.0f;
        r.j[t] = ok ? j : 11;
    }
    return r;
}

// ---------------------------------------------------------------------------
// 0. fp32 -> (hi, lo) bf16 split. n4 = element_count / 4.
// ---------------------------------------------------------------------------
__global__ __launch_bounds__(256) void split_kernel(
    const float* __restrict__ in, ushort_t* __restrict__ hi,
    ushort_t* __restrict__ lo, int n4)
{
    const int i = blockIdx.x * 256 + threadIdx.x;
    if (i >= n4) return;
    const float4 f = reinterpret_cast<const float4*>(in)[i];
    const ushort_t h0 = f2bf(f.x), h1 = f2bf(f.y), h2 = f2bf(f.z), h3 = f2bf(f.w);
    ushort4 hv; hv.x = h0; hv.y = h1; hv.z = h2; hv.w = h3;
    ushort4 lv;
    lv.x = f2bf(f.x - bf2f(h0)); lv.y = f2bf(f.y - bf2f(h1));
    lv.z = f2bf(f.z - bf2f(h2)); lv.w = f2bf(f.w - bf2f(h3));
    reinterpret_cast<ushort4*>(hi)[i] = hv;
    reinterpret_cast<ushort4*>(lo)[i] = lv;
}

// ---------------------------------------------------------------------------
// 1. eta: one wave per (b,s) row, loops h=0..15. eta[((b*16+h)*128+n)*16+m]
// ---------------------------------------------------------------------------
__global__ __launch_bounds__(256) void eta_kernel(
    const float* __restrict__ x, const float* __restrict__ lrW,
    const float* __restrict__ lrb, const float* __restrict__ gsc,
    float* __restrict__ eta)
{
    const int row = blockIdx.x * 4 + (threadIdx.x >> 6);
    const int lane = threadIdx.x & 63;
    float xv[16];
#pragma unroll
    for (int i = 0; i < 16; ++i) xv[i] = x[(size_t)row * 1024 + lane + i * 64];
    const int b = row >> 11, s = row & 2047, n = s >> 4, m = s & 15;
    const float gs = fmaxf(1.0f / (float)(m + 1) + gsc[m], 0.0f);
    for (int h = 0; h < 16; ++h) {
        float acc = 0.0f;
#pragma unroll
        for (int i = 0; i < 16; ++i) acc += xv[i] * lrW[h * 1024 + lane + i * 64];
#pragma unroll
        for (int off = 32; off > 0; off >>= 1) acc += __shfl_xor(acc, off, 64);
        if (lane == 0) {
            float sig = 1.0f / (1.0f + expf(-(acc + lrb[h])));
            eta[(((size_t)(b * 16 + h)) * 128 + n) * 16 + m] = (sig / 64.0f) * gs;
        }
    }
}

// ---------------------------------------------------------------------------
// 2. QKV GEMM: m97-style 128x128 tile, BK=32, global_load_lds(16B), split
//    bf16 3-pass accumulation, fused RoPE epilogue.
//    grid (M/128=64, 3*1024/128=24), 256 threads (4 waves, 2x2 of 64x64).
// ---------------------------------------------------------------------------
__global__ __launch_bounds__(256) void qkv_rope_kernel(
    const ushort_t* __restrict__ xh, const ushort_t* __restrict__ xl,
    const ushort_t* __restrict__ Wqh, const ushort_t* __restrict__ Wql,
    const ushort_t* __restrict__ Wkh, const ushort_t* __restrict__ Wkl,
    const ushort_t* __restrict__ Wvh, const ushort_t* __restrict__ Wvl,
    const float* __restrict__ posf,
    float* __restrict__ Qb, float* __restrict__ Kb, float* __restrict__ Vb)
{
    __shared__ ushort_t As[2][128 * 32];   // [hi/lo][row][k]
    __shared__ ushort_t Bs[2][128 * 32];   // [hi/lo][col][k]

    const int tid = threadIdx.x;
    const int wv = tid >> 6, ln = tid & 63;
    const int l15 = ln & 15, lq = ln >> 4;
    const int wm = wv >> 1, wn = wv & 1;
    const int rowbase = blockIdx.x * 128;
    const int colbase = blockIdx.y * 128;
    const int sel = colbase >> 10;                 // 0=Q 1=K 2=V (uniform)
    const ushort_t* Bh = (sel == 0) ? Wqh : (sel == 1) ? Wkh : Wvh;
    const ushort_t* Bl = (sel == 0) ? Wql : (sel == 1) ? Wkl : Wvl;
    float* dst = (sel == 0) ? Qb : (sel == 1) ? Kb : Vb;
    const int colm = colbase & 1023;

    // wave wv stages buffer wv: 0=Ah 1=Al 2=Bh 3=Bl
    const ushort_t* gsrc = (wv == 0) ? xh : (wv == 1) ? xl : (wv == 2) ? Bh : Bl;
    ushort_t* lbase = (wv == 0) ? &As[0][0] : (wv == 1) ? &As[1][0]
                    : (wv == 2) ? &Bs[0][0] : &Bs[1][0];
    const int grow = ((wv < 2) ? rowbase : colm) + (ln >> 2);
    const ushort_t* gs = gsrc + (size_t)grow * 1024 + (ln & 3) * 8;

    f32x4 acc[4][4] = {};
    for (int k0 = 0; k0 < 1024; k0 += 32) {
#pragma unroll
        for (int j = 0; j < 8; ++j)
            GLOAD_LDS16(gs + (size_t)j * 16 * 1024 + k0, lbase + j * 512);
        __syncthreads();

        bf16x8 ah[4], al[4], bh[4], bl[4];
#pragma unroll
        for (int t = 0; t < 4; ++t) {
            const int ar = (wm * 64 + t * 16 + l15) * 32 + lq * 8;
            ah[t] = *reinterpret_cast<const bf16x8*>(&As[0][ar]);
            al[t] = *reinterpret_cast<const bf16x8*>(&As[1][ar]);
            const int br = (wn * 64 + t * 16 + l15) * 32 + lq * 8;
            bh[t] = *reinterpret_cast<const bf16x8*>(&Bs[0][br]);
            bl[t] = *reinterpret_cast<const bf16x8*>(&Bs[1][br]);
        }
#pragma unroll
        for (int mt = 0; mt < 4; ++mt)
#pragma unroll
            for (int nt = 0; nt < 4; ++nt) {
                acc[mt][nt] = __builtin_amdgcn_mfma_f32_16x16x32_bf16(ah[mt], bh[nt], acc[mt][nt], 0, 0, 0);
                acc[mt][nt] = __builtin_amdgcn_mfma_f32_16x16x32_bf16(ah[mt], bl[nt], acc[mt][nt], 0, 0, 0);
                acc[mt][nt] = __builtin_amdgcn_mfma_f32_16x16x32_bf16(al[mt], bh[nt], acc[mt][nt], 0, 0, 0);
            }
        __syncthreads();
    }

    // epilogue: RoPE + scatter to [b][h][n][m][d]
#pragma unroll
    for (int mt = 0; mt < 4; ++mt)
#pragma unroll
        for (int nt = 0; nt < 4; ++nt) {
            const int col = colm + wn * 64 + nt * 16 + l15;  // col in matrix
            const int d = col & 63, h = col >> 6;
            const int angidx = d >> 1;
            const int odd = d & 1;
#pragma unroll
            for (int r = 0; r < 4; ++r) {
                const int row = rowbase + wm * 64 + mt * 16 + lq * 4 + r;
                const int b = row >> 11, s = row & 2047;
                const float ang = posf[s * 32 + angidx];
                const float c = cosf(ang), sn = sinf(ang);
                const float own = acc[mt][nt][r];
                const float partner = __shfl_xor(own, 1, 64);
                const float res = odd ? (partner * sn + own * c)
                                      : (own * c - partner * sn);
                const int n = s >> 4, m = s & 15;
                dst[(((size_t)(b * 16 + h)) * 128 + n) * 1024 + m * 64 + d] = res;
            }
        }
}

// ---------------------------------------------------------------------------
// 3. TTT scan: 64 blocks (one per (b,h)), 1024 threads (wave=m, lane=d).
// ---------------------------------------------------------------------------
__global__ __launch_bounds__(1024) void scan_kernel(
    const float* __restrict__ Qb, const float* __restrict__ Kb,
    const float* __restrict__ Vb, const float* __restrict__ eta,
    const float* __restrict__ tg, const float* __restrict__ tb,
    const float* __restrict__ coeff, float* __restrict__ out_pre)
{
    __shared__ float Wl[12 * 64];        // rows 0..10 = W, row 11 = zeros
    __shared__ float cum[16 * 12 * 64];  // 48 KiB

    const int tid = threadIdx.x;
    const int m = tid >> 6, d = tid & 63;
    const int b = blockIdx.x >> 4, h = blockIdx.x & 15;

    const float gam = tg[h * 64 + d];
    const float bet = tb[h * 64 + d];
    if (tid < 768) Wl[tid] = (tid < 704) ? coeff[h * 704 + tid] : 0.0f;
    __syncthreads();

    const size_t base = ((size_t)(b * 16 + h)) * 131072;
    const float* Qp = Qb + base;
    const float* Kp = Kb + base;
    const float* Vp = Vb + base;
    const float* ep = eta + ((size_t)(b * 16 + h)) * 2048;

    float kf = Kp[tid], vf = Vp[tid], qf = Qp[tid], ei = ep[m];

    for (int n = 0; n < 128; ++n) {
        const int n1 = (n < 127) ? n + 1 : n;
        const float kfN = Kp[n1 * 1024 + tid];
        const float vfN = Vp[n1 * 1024 + tid];
        const float qfN = Qp[n1 * 1024 + tid];
        const float eiN = ep[n1 * 16 + m];

        const Bas4 bk = bspline4(kf);
        float zk = silu(kf);
#pragma unroll
        for (int t = 0; t < 4; ++t)
            zk = fmaf(bk.n[t], Wl[bk.j[t] * 64 + d], zk);

        float s1 = zk, s2 = zk * zk;
        wave_reduce2(s1, s2);
        const float mu = s1 * (1.0f / 64.0f);
        const float var = s2 * (1.0f / 64.0f) - mu * mu;
        const float rstd = rsqrtf(var + 1e-6f);
        const float xhat = (zk - mu) * rstd;
        const float gxh = (gam * xhat + bet - (vf - kf)) * gam;
        float t1 = gxh, t2 = gxh * xhat;
        wave_reduce2(t1, t2);
        const float gz = (gxh - t1 * (1.0f / 64.0f) - xhat * (t2 * (1.0f / 64.0f))) * rstd;

        const float tokf = ei * gz;
#pragma unroll
        for (int j = 0; j < 12; ++j) cum[m * 768 + j * 64 + d] = 0.0f;
#pragma unroll
        for (int t = 0; t < 4; ++t)
            cum[m * 768 + bk.j[t] * 64 + d] = tokf * bk.n[t];
        __syncthreads();

        if (tid < 704) {
            float a = Wl[tid];
#pragma unroll
            for (int mm = 0; mm < 16; ++mm) {
                a -= cum[mm * 768 + tid];
                cum[mm * 768 + tid] = a;
            }
            Wl[tid] = a;
        }
        __syncthreads();

        const Bas4 bq = bspline4(qf);
        float zq = silu(qf);
#pragma unroll
        for (int t = 0; t < 4; ++t)
            zq = fmaf(bq.n[t], cum[m * 768 + bq.j[t] * 64 + d], zq);

        float u1 = zq, u2 = zq * zq;
        wave_reduce2(u1, u2);
        const float mu2 = u1 * (1.0f / 64.0f);
        const float var2 = u2 * (1.0f / 64.0f) - mu2 * mu2;
        const float rstd2 = rsqrtf(var2 + 1e-6f);
        const float y = qf + gam * (zq - mu2) * rstd2 + bet;
        out_pre[((size_t)b * 2048 + n * 16 + m) * 1024 + h * 64 + d] = y;

        __syncthreads();
        kf = kfN; vf = vfN; qf = qfN; ei = eiN;
    }
}

// ---------------------------------------------------------------------------
// 4. Final LayerNorm over DIM=1024 -> (hi, lo) bf16 for the split out-GEMM.
// ---------------------------------------------------------------------------
__global__ __launch_bounds__(256) void ln_kernel(
    const float* __restrict__ in, const float* __restrict__ pw,
    const float* __restrict__ pb, ushort_t* __restrict__ hi,
    ushort_t* __restrict__ lo)
{
    const int row = blockIdx.x * 4 + (threadIdx.x >> 6);
    const int lane = threadIdx.x & 63;
    const float* r = in + (size_t)row * 1024;
    float v[16];
    float s1 = 0.0f, s2 = 0.0f;
#pragma unroll
    for (int i = 0; i < 16; ++i) {
        v[i] = r[lane + i * 64];
        s1 += v[i];
        s2 += v[i] * v[i];
    }
    wave_reduce2(s1, s2);
    const float mu = s1 * (1.0f / 1024.0f);
    const float var = s2 * (1.0f / 1024.0f) - mu * mu;
    const float rstd = rsqrtf(var + 1e-6f);
#pragma unroll
    for (int i = 0; i < 16; ++i) {
        const int c = lane + i * 64;
        const float o = (v[i] - mu) * rstd * pw[c] + pb[c];
        const ushort_t h = f2bf(o);
        hi[(size_t)row * 1024 + c] = h;
        lo[(size_t)row * 1024 + c] = f2bf(o - bf2f(h));
    }
}

// ---------------------------------------------------------------------------
// 5. Output GEMM: same m97-style tiled split GEMM; plain fp32 epilogue.
//    grid (64, 8), 256 threads.
// ---------------------------------------------------------------------------
__global__ __launch_bounds__(256) void out_gemm_kernel(
    const ushort_t* __restrict__ Ah, const ushort_t* __restrict__ Al,
    const ushort_t* __restrict__ Wh, const ushort_t* __restrict__ Wlo,
    float* __restrict__ out)
{
    __shared__ ushort_t As[2][128 * 32];
    __shared__ ushort_t Bs[2][128 * 32];

    const int tid = threadIdx.x;
    const int wv = tid >> 6, ln = tid & 63;
    const int l15 = ln & 15, lq = ln >> 4;
    const int wm = wv >> 1, wn = wv & 1;
    const int rowbase = blockIdx.x * 128;
    const int colbase = blockIdx.y * 128;

    const ushort_t* gsrc = (wv == 0) ? Ah : (wv == 1) ? Al : (wv == 2) ? Wh : Wlo;
    ushort_t* lbase = (wv == 0) ? &As[0][0] : (wv == 1) ? &As[1][0]
                    : (wv == 2) ? &Bs[0][0] : &Bs[1][0];
    const int grow = ((wv < 2) ? rowbase : colbase) + (ln >> 2);
    const ushort_t* gs = gsrc + (size_t)grow * 1024 + (ln & 3) * 8;

    f32x4 acc[4][4] = {};
    for (int k0 = 0; k0 < 1024; k0 += 32) {
#pragma unroll
        for (int j = 0; j < 8; ++j)
            GLOAD_LDS16(gs + (size_t)j * 16 * 1024 + k0, lbase + j * 512);
        __syncthreads();

        bf16x8 ah[4], al[4], bh[4], bl[4];
#pragma unroll
        for (int t = 0; t < 4; ++t) {
            const int ar = (wm * 64 + t * 16 + l15) * 32 + lq * 8;
            ah[t] = *reinterpret_cast<const bf16x8*>(&As[0][ar]);
            al[t] = *reinterpret_cast<const bf16x8*>(&As[1][ar]);
            const int br = (wn * 64 + t * 16 + l15) * 32 + lq * 8;
            bh[t] = *reinterpret_cast<const bf16x8*>(&Bs[0][br]);
            bl[t] = *reinterpret_cast<const bf16x8*>(&Bs[1][br]);
        }
#pragma unroll
        for (int mt = 0; mt < 4; ++mt)
#pragma unroll
            for (int nt = 0; nt < 4; ++nt) {
                acc[mt][nt] = __builtin_amdgcn_mfma_f32_16x16x32_bf16(ah[mt], bh[nt], acc[mt][nt], 0, 0, 0);
                acc[mt][nt] = __builtin_amdgcn_mfma_f32_16x16x32_bf16(ah[mt], bl[nt], acc[mt][nt], 0, 0, 0);
                acc[mt][nt] = __builtin_amdgcn_mfma_f32_16x16x32_bf16(al[mt], bh[nt], acc[mt][nt], 0, 0, 0);
            }
        __syncthreads();
    }

#pragma unroll
    for (int mt = 0; mt < 4; ++mt)
#pragma unroll
        for (int nt = 0; nt < 4; ++nt) {
            const int col = colbase + wn * 64 + nt * 16 + l15;
#pragma unroll
            for (int r = 0; r < 4; ++r) {
                const int row = rowbase + wm * 64 + mt * 16 + lq * 4 + r;
                out[(size_t)row * 1024 + col] = acc[mt][nt][r];
            }
        }
}

// ---------------------------------------------------------------------------
extern "C" void kernel_launch(void* const* d_in, const int* in_sizes, int n_in,
                              void* d_out, int out_size, void* d_ws, size_t ws_size,
                              hipStream_t stream) {
    const float* x    = (const float*)d_in[0];
    const float* posf = (const float*)d_in[1];
    const float* Wq   = (const float*)d_in[2];
    const float* Wk   = (const float*)d_in[3];
    const float* Wv   = (const float*)d_in[4];
    const float* Wo   = (const float*)d_in[5];
    const float* lrW  = (const float*)d_in[6];
    const float* lrb  = (const float*)d_in[7];
    const float* gsc  = (const float*)d_in[8];
    const float* tg   = (const float*)d_in[9];
    const float* tb   = (const float*)d_in[10];
    const float* pw   = (const float*)d_in[11];
    const float* pb   = (const float*)d_in[12];
    const float* coeff= (const float*)d_in[13];
    // d_in[14] = knots: uniform linspace(-1,1,15); closed-form in scan.

    char* ws = (char*)d_ws;
    float*    Qb   = (float*)(ws);                      // 32 MB [dead after scan]
    float*    Kb   = (float*)(ws + 33554432);           // 32 MB [dead after scan]
    float*    Vb   = (float*)(ws + 67108864);           // 32 MB
    ushort_t* xh   = (ushort_t*)(ws + 100663296);       // 16 MB [dead after qkv]
    ushort_t* xl   = (ushort_t*)(ws + 117440512);       // 16 MB
    float*    outp = (float*)(ws + 100663296);          // 32 MB (aliases xh+xl)
    float*    eta  = (float*)(ws + 134217728);          // 0.5 MB
    ushort_t* Wqh  = (ushort_t*)(ws + 134742016);       // 2 MB each
    ushort_t* Wql  = (ushort_t*)(ws + 136839168);
    ushort_t* Wkh  = (ushort_t*)(ws + 138936320);
    ushort_t* Wkl  = (ushort_t*)(ws + 141033472);
    ushort_t* Wvh  = (ushort_t*)(ws + 143130624);
    ushort_t* Wvl  = (ushort_t*)(ws + 145227776);
    ushort_t* Woh  = (ushort_t*)(ws + 147324928);
    ushort_t* Wol  = (ushort_t*)(ws + 149422080);       // end 151519232
    ushort_t* lnh  = (ushort_t*)(ws);                   // aliases Qb (dead)
    ushort_t* lnl  = (ushort_t*)(ws + 16777216);

    split_kernel<<<8192, 256, 0, stream>>>(x,  xh,  xl,  2097152);
    split_kernel<<<1024, 256, 0, stream>>>(Wq, Wqh, Wql, 262144);
    split_kernel<<<1024, 256, 0, stream>>>(Wk, Wkh, Wkl, 262144);
    split_kernel<<<1024, 256, 0, stream>>>(Wv, Wvh, Wvl, 262144);
    split_kernel<<<1024, 256, 0, stream>>>(Wo, Woh, Wol, 262144);
    eta_kernel<<<2048, 256, 0, stream>>>(x, lrW, lrb, gsc, eta);
    qkv_rope_kernel<<<dim3(64, 24), 256, 0, stream>>>(xh, xl, Wqh, Wql, Wkh, Wkl,
                                                      Wvh, Wvl, posf, Qb, Kb, Vb);
    scan_kernel<<<64, 1024, 0, stream>>>(Qb, Kb, Vb, eta, tg, tb, coeff, outp);
    ln_kernel<<<2048, 256, 0, stream>>>(outp, pw, pb, lnh, lnl);
    out_gemm_kernel<<<dim3(64, 8), 256, 0, stream>>>(lnh, lnl, Woh, Wol, (float*)d_out);
}

// Round 5
// 798.934 us; speedup vs baseline: 2.0673x; 2.0673x over previous
//
#include <hip/hip_runtime.h>
#include <stdint.h>

// ---------------------------------------------------------------------------
// T3KAN pipeline on MI355X. ALL inputs and the output are float32.
//
//  0. split_kernel    : fp32 -> (hi,lo) bf16 for x, Wq, Wk, Wv, Wo
//  1. eta_kernel      : lr = sigmoid(x . lrW_h + b_h)/64 * gs[m]  -> eta fp32
//  2. qkv_rope_kernel : QKV = x @ W^T, 3-pass split-bf16 MFMA, 128x128 LDS
//                       tiles staged via vector-load + ds_write (NOT
//                       global_load_lds: R4 showed it defeats L2 reuse here —
//                       FETCH 372MB->1.8GB, WRITE 116MB->3.35GB, 63% HBM-bound)
//                       + fused RoPE epilogue.
//  3. scan_kernel     : 128-step TTT scan (sparse uniform-knot B-spline)
//  4. ln_kernel       : final LayerNorm -> (hi,lo) bf16
//  5. out_gemm_kernel : ln @ Wo^T, same tiled split GEMM -> fp32
// ---------------------------------------------------------------------------

typedef unsigned short ushort_t;
typedef short bf16x8 __attribute__((ext_vector_type(8)));
typedef float f32x4 __attribute__((ext_vector_type(4)));

// LDS tile row stride: 40 ushorts = 80 B -> bank stride 20 -> 2-way lane
// aliasing on ds_read_b128 (free per m136), vs 64 B stride's 8-way.
#define LSTRIDE 40

__device__ __forceinline__ float bf2f(ushort_t u) {
    union { uint32_t i; float f; } v; v.i = ((uint32_t)u) << 16; return v.f;
}
__device__ __forceinline__ ushort_t f2bf(float f) {   // RNE fp32->bf16
    union { float f; uint32_t i; } v; v.f = f;
    uint32_t r = v.i + 0x7FFFu + ((v.i >> 16) & 1u);
    return (ushort_t)(r >> 16);
}
__device__ __forceinline__ float silu(float x) { return x / (1.0f + expf(-x)); }

__device__ __forceinline__ void wave_reduce2(float& a, float& b) {
#pragma unroll
    for (int off = 32; off > 0; off >>= 1) {
        a += __shfl_xor(a, off, 64);
        b += __shfl_xor(b, off, 64);
    }
}

// ---------------------------------------------------------------------------
// Sparse degree-3 B-spline on UNIFORM knots linspace(-1,1,15), delta=1/7.
// 4 nonzero basis values; j-slot 11 is a dummy zero. Zero divides.
// ---------------------------------------------------------------------------
struct Bas4 { float n[4]; int j[4]; };
__device__ __forceinline__ Bas4 bspline4(float x) {
    const float DELTA = 0.14285714285714285f;  // 1/7
    const float xp1 = x + 1.0f;
    const float fi = floorf(xp1 * 7.0f);
    const bool valid = (fi >= 0.0f) && (fi <= 13.0f);
    const float fic = valid ? fi : 0.0f;
    const float left1  = xp1 - fic * DELTA;
    const float left2  = xp1 - (fic - 1.0f) * DELTA;
    const float left3  = xp1 - (fic - 2.0f) * DELTA;
    const float right1 = (fic + 1.0f) * DELTA - xp1;
    const float right2 = (fic + 2.0f) * DELTA - xp1;
    const float right3 = (fic + 3.0f) * DELTA - xp1;
    float N0, N1, N2, N3, saved, temp;
    temp = 7.0f;
    N0 = right1 * temp;
    N1 = left1 * temp;
    temp = N0 * 3.5f;
    N0 = right1 * temp; saved = left2 * temp;
    temp = N1 * 3.5f;
    N1 = fmaf(right2, temp, saved);
    N2 = left1 * temp;
    const float inv3 = 2.3333333333333335f;
    temp = N0 * inv3;
    N0 = right1 * temp; saved = left3 * temp;
    temp = N1 * inv3;
    N1 = fmaf(right2, temp, saved); saved = left2 * temp;
    temp = N2 * inv3;
    N2 = fmaf(right3, temp, saved);
    N3 = left1 * temp;

    Bas4 r;
    const int i = (int)fic;
    const float nv[4] = {N0, N1, N2, N3};
#pragma unroll
    for (int t = 0; t < 4; ++t) {
        const int j = i - 3 + t;
        const bool ok = valid && (j >= 0) && (j <= 10);
        r.n[t] = ok ? nv[t] : 0.0f;
        r.j[t] = ok ? j : 11;
    }
    return r;
}

// ---------------------------------------------------------------------------
// 0. fp32 -> (hi, lo) bf16 split. n4 = element_count / 4.
// ---------------------------------------------------------------------------
__global__ __launch_bounds__(256) void split_kernel(
    const float* __restrict__ in, ushort_t* __restrict__ hi,
    ushort_t* __restrict__ lo, int n4)
{
    const int i = blockIdx.x * 256 + threadIdx.x;
    if (i >= n4) return;
    const float4 f = reinterpret_cast<const float4*>(in)[i];
    const ushort_t h0 = f2bf(f.x), h1 = f2bf(f.y), h2 = f2bf(f.z), h3 = f2bf(f.w);
    ushort4 hv; hv.x = h0; hv.y = h1; hv.z = h2; hv.w = h3;
    ushort4 lv;
    lv.x = f2bf(f.x - bf2f(h0)); lv.y = f2bf(f.y - bf2f(h1));
    lv.z = f2bf(f.z - bf2f(h2)); lv.w = f2bf(f.w - bf2f(h3));
    reinterpret_cast<ushort4*>(hi)[i] = hv;
    reinterpret_cast<ushort4*>(lo)[i] = lv;
}

// ---------------------------------------------------------------------------
// 1. eta: one wave per (b,s) row, loops h=0..15. eta[((b*16+h)*128+n)*16+m]
// ---------------------------------------------------------------------------
__global__ __launch_bounds__(256) void eta_kernel(
    const float* __restrict__ x, const float* __restrict__ lrW,
    const float* __restrict__ lrb, const float* __restrict__ gsc,
    float* __restrict__ eta)
{
    const int row = blockIdx.x * 4 + (threadIdx.x >> 6);
    const int lane = threadIdx.x & 63;
    float xv[16];
#pragma unroll
    for (int i = 0; i < 16; ++i) xv[i] = x[(size_t)row * 1024 + lane + i * 64];
    const int b = row >> 11, s = row & 2047, n = s >> 4, m = s & 15;
    const float gs = fmaxf(1.0f / (float)(m + 1) + gsc[m], 0.0f);
    for (int h = 0; h < 16; ++h) {
        float acc = 0.0f;
#pragma unroll
        for (int i = 0; i < 16; ++i) acc += xv[i] * lrW[h * 1024 + lane + i * 64];
#pragma unroll
        for (int off = 32; off > 0; off >>= 1) acc += __shfl_xor(acc, off, 64);
        if (lane == 0) {
            float sig = 1.0f / (1.0f + expf(-(acc + lrb[h])));
            eta[(((size_t)(b * 16 + h)) * 128 + n) * 16 + m] = (sig / 64.0f) * gs;
        }
    }
}

// ---------------------------------------------------------------------------
// Shared GEMM body: 512 threads = 8 waves (2 row-halves x 4 col-quarters),
// block tile 128x128, BK=32, LDS staged via vector loads + ds_write_b128,
// one-tile register prefetch. Wave tile 64x32 -> acc[4][2], 24 MFMA per k0.
// Computes acc = A(rows) . B(cols)^T in 3-pass split-bf16.
// ---------------------------------------------------------------------------
#define GEMM_TILE_BODY(Ah_g, Al_g, Bh_g, Bl_g, rowbase, colb)                  \
    __shared__ __align__(16) ushort_t Ash[128 * LSTRIDE];                      \
    __shared__ __align__(16) ushort_t Asl[128 * LSTRIDE];                      \
    __shared__ __align__(16) ushort_t Bsh[128 * LSTRIDE];                      \
    __shared__ __align__(16) ushort_t Bsl[128 * LSTRIDE];                      \
    const int tid = threadIdx.x;                                               \
    const int wv = tid >> 6, ln = tid & 63;                                    \
    const int l15 = ln & 15, lq = ln >> 4;                                     \
    const int wm = wv >> 2, wn = wv & 3;                                       \
    const int srow = tid >> 2;               /* 0..127 */                      \
    const int skseg = (tid & 3) * 8;         /* 0,8,16,24 */                   \
    const ushort_t* gA_h = (Ah_g) + (size_t)((rowbase) + srow) * 1024 + skseg; \
    const ushort_t* gA_l = (Al_g) + (size_t)((rowbase) + srow) * 1024 + skseg; \
    const ushort_t* gB_h = (Bh_g) + (size_t)((colb) + srow) * 1024 + skseg;    \
    const ushort_t* gB_l = (Bl_g) + (size_t)((colb) + srow) * 1024 + skseg;    \
    const int sw = srow * LSTRIDE + skseg;                                     \
    f32x4 acc[4][2] = {};                                                      \
    bf16x8 rAh = *reinterpret_cast<const bf16x8*>(gA_h);                       \
    bf16x8 rAl = *reinterpret_cast<const bf16x8*>(gA_l);                       \
    bf16x8 rBh = *reinterpret_cast<const bf16x8*>(gB_h);                       \
    bf16x8 rBl = *reinterpret_cast<const bf16x8*>(gB_l);                       \
    for (int k0 = 0; k0 < 1024; k0 += 32) {                                    \
        *reinterpret_cast<bf16x8*>(&Ash[sw]) = rAh;                            \
        *reinterpret_cast<bf16x8*>(&Asl[sw]) = rAl;                            \
        *reinterpret_cast<bf16x8*>(&Bsh[sw]) = rBh;                            \
        *reinterpret_cast<bf16x8*>(&Bsl[sw]) = rBl;                            \
        __syncthreads();                                                       \
        const int kn = k0 + 32;                                                \
        if (kn < 1024) {                                                       \
            rAh = *reinterpret_cast<const bf16x8*>(gA_h + kn);                 \
            rAl = *reinterpret_cast<const bf16x8*>(gA_l + kn);                 \
            rBh = *reinterpret_cast<const bf16x8*>(gB_h + kn);                 \
            rBl = *reinterpret_cast<const bf16x8*>(gB_l + kn);                 \
        }                                                                      \
        bf16x8 bh[2], bl[2];                                                   \
        _Pragma("unroll")                                                      \
        for (int u = 0; u < 2; ++u) {                                          \
            const int br = (wn * 32 + u * 16 + l15) * LSTRIDE + lq * 8;        \
            bh[u] = *reinterpret_cast<const bf16x8*>(&Bsh[br]);                \
            bl[u] = *reinterpret_cast<const bf16x8*>(&Bsl[br]);                \
        }                                                                      \
        _Pragma("unroll")                                                      \
        for (int t = 0; t < 4; ++t) {                                          \
            const int ar = (wm * 64 + t * 16 + l15) * LSTRIDE + lq * 8;        \
            const bf16x8 ah = *reinterpret_cast<const bf16x8*>(&Ash[ar]);      \
            const bf16x8 al = *reinterpret_cast<const bf16x8*>(&Asl[ar]);      \
            _Pragma("unroll")                                                  \
            for (int u = 0; u < 2; ++u) {                                      \
                acc[t][u] = __builtin_amdgcn_mfma_f32_16x16x32_bf16(ah, bh[u], acc[t][u], 0, 0, 0); \
                acc[t][u] = __builtin_amdgcn_mfma_f32_16x16x32_bf16(ah, bl[u], acc[t][u], 0, 0, 0); \
                acc[t][u] = __builtin_amdgcn_mfma_f32_16x16x32_bf16(al, bh[u], acc[t][u], 0, 0, 0); \
            }                                                                  \
        }                                                                      \
        __syncthreads();                                                       \
    }

// ---------------------------------------------------------------------------
// 2. QKV GEMM + RoPE. grid (8192/128=64, 3*1024/128=24), 512 threads.
// ---------------------------------------------------------------------------
__global__ __launch_bounds__(512) void qkv_rope_kernel(
    const ushort_t* __restrict__ xh, const ushort_t* __restrict__ xl,
    const ushort_t* __restrict__ Wqh, const ushort_t* __restrict__ Wql,
    const ushort_t* __restrict__ Wkh, const ushort_t* __restrict__ Wkl,
    const ushort_t* __restrict__ Wvh, const ushort_t* __restrict__ Wvl,
    const float* __restrict__ posf,
    float* __restrict__ Qb, float* __restrict__ Kb, float* __restrict__ Vb)
{
    const int rowbase = blockIdx.x * 128;
    const int colbase = blockIdx.y * 128;
    const int sel = colbase >> 10;                 // 0=Q 1=K 2=V (uniform)
    const ushort_t* WBh = (sel == 0) ? Wqh : (sel == 1) ? Wkh : Wvh;
    const ushort_t* WBl = (sel == 0) ? Wql : (sel == 1) ? Wkl : Wvl;
    float* dst = (sel == 0) ? Qb : (sel == 1) ? Kb : Vb;
    const int colm = colbase & 1023;

    GEMM_TILE_BODY(xh, xl, WBh, WBl, rowbase, colm)

    // epilogue: RoPE + scatter to [b][h][n][m][d]
#pragma unroll
    for (int t = 0; t < 4; ++t)
#pragma unroll
        for (int u = 0; u < 2; ++u) {
            const int col = colm + wn * 32 + u * 16 + l15;  // col in matrix
            const int d = col & 63, h = col >> 6;
            const int angidx = d >> 1;
            const int odd = d & 1;
#pragma unroll
            for (int r = 0; r < 4; ++r) {
                const int row = rowbase + wm * 64 + t * 16 + lq * 4 + r;
                const int b = row >> 11, s = row & 2047;
                const float ang = posf[s * 32 + angidx];
                const float c = cosf(ang), sn = sinf(ang);
                const float own = acc[t][u][r];
                const float partner = __shfl_xor(own, 1, 64);
                const float res = odd ? (partner * sn + own * c)
                                      : (own * c - partner * sn);
                const int n = s >> 4, m = s & 15;
                dst[(((size_t)(b * 16 + h)) * 128 + n) * 1024 + m * 64 + d] = res;
            }
        }
}

// ---------------------------------------------------------------------------
// 3. TTT scan: 64 blocks (one per (b,h)), 1024 threads (wave=m, lane=d).
// ---------------------------------------------------------------------------
__global__ __launch_bounds__(1024) void scan_kernel(
    const float* __restrict__ Qb, const float* __restrict__ Kb,
    const float* __restrict__ Vb, const float* __restrict__ eta,
    const float* __restrict__ tg, const float* __restrict__ tb,
    const float* __restrict__ coeff, float* __restrict__ out_pre)
{
    __shared__ float Wl[12 * 64];        // rows 0..10 = W, row 11 = zeros
    __shared__ float cum[16 * 12 * 64];  // 48 KiB

    const int tid = threadIdx.x;
    const int m = tid >> 6, d = tid & 63;
    const int b = blockIdx.x >> 4, h = blockIdx.x & 15;

    const float gam = tg[h * 64 + d];
    const float bet = tb[h * 64 + d];
    if (tid < 768) Wl[tid] = (tid < 704) ? coeff[h * 704 + tid] : 0.0f;
    __syncthreads();

    const size_t base = ((size_t)(b * 16 + h)) * 131072;
    const float* Qp = Qb + base;
    const float* Kp = Kb + base;
    const float* Vp = Vb + base;
    const float* ep = eta + ((size_t)(b * 16 + h)) * 2048;

    float kf = Kp[tid], vf = Vp[tid], qf = Qp[tid], ei = ep[m];

    for (int n = 0; n < 128; ++n) {
        const int n1 = (n < 127) ? n + 1 : n;
        const float kfN = Kp[n1 * 1024 + tid];
        const float vfN = Vp[n1 * 1024 + tid];
        const float qfN = Qp[n1 * 1024 + tid];
        const float eiN = ep[n1 * 16 + m];

        const Bas4 bk = bspline4(kf);
        float zk = silu(kf);
#pragma unroll
        for (int t = 0; t < 4; ++t)
            zk = fmaf(bk.n[t], Wl[bk.j[t] * 64 + d], zk);

        float s1 = zk, s2 = zk * zk;
        wave_reduce2(s1, s2);
        const float mu = s1 * (1.0f / 64.0f);
        const float var = s2 * (1.0f / 64.0f) - mu * mu;
        const float rstd = rsqrtf(var + 1e-6f);
        const float xhat = (zk - mu) * rstd;
        const float gxh = (gam * xhat + bet - (vf - kf)) * gam;
        float t1 = gxh, t2 = gxh * xhat;
        wave_reduce2(t1, t2);
        const float gz = (gxh - t1 * (1.0f / 64.0f) - xhat * (t2 * (1.0f / 64.0f))) * rstd;

        const float tokf = ei * gz;
#pragma unroll
        for (int j = 0; j < 12; ++j) cum[m * 768 + j * 64 + d] = 0.0f;
#pragma unroll
        for (int t = 0; t < 4; ++t)
            cum[m * 768 + bk.j[t] * 64 + d] = tokf * bk.n[t];
        __syncthreads();

        if (tid < 704) {
            float a = Wl[tid];
#pragma unroll
            for (int mm = 0; mm < 16; ++mm) {
                a -= cum[mm * 768 + tid];
                cum[mm * 768 + tid] = a;
            }
            Wl[tid] = a;
        }
        __syncthreads();

        const Bas4 bq = bspline4(qf);
        float zq = silu(qf);
#pragma unroll
        for (int t = 0; t < 4; ++t)
            zq = fmaf(bq.n[t], cum[m * 768 + bq.j[t] * 64 + d], zq);

        float u1 = zq, u2 = zq * zq;
        wave_reduce2(u1, u2);
        const float mu2 = u1 * (1.0f / 64.0f);
        const float var2 = u2 * (1.0f / 64.0f) - mu2 * mu2;
        const float rstd2 = rsqrtf(var2 + 1e-6f);
        const float y = qf + gam * (zq - mu2) * rstd2 + bet;
        out_pre[((size_t)b * 2048 + n * 16 + m) * 1024 + h * 64 + d] = y;

        __syncthreads();
        kf = kfN; vf = vfN; qf = qfN; ei = eiN;
    }
}

// ---------------------------------------------------------------------------
// 4. Final LayerNorm over DIM=1024 -> (hi, lo) bf16 for the split out-GEMM.
// ---------------------------------------------------------------------------
__global__ __launch_bounds__(256) void ln_kernel(
    const float* __restrict__ in, const float* __restrict__ pw,
    const float* __restrict__ pb, ushort_t* __restrict__ hi,
    ushort_t* __restrict__ lo)
{
    const int row = blockIdx.x * 4 + (threadIdx.x >> 6);
    const int lane = threadIdx.x & 63;
    const float* r = in + (size_t)row * 1024;
    float v[16];
    float s1 = 0.0f, s2 = 0.0f;
#pragma unroll
    for (int i = 0; i < 16; ++i) {
        v[i] = r[lane + i * 64];
        s1 += v[i];
        s2 += v[i] * v[i];
    }
    wave_reduce2(s1, s2);
    const float mu = s1 * (1.0f / 1024.0f);
    const float var = s2 * (1.0f / 1024.0f) - mu * mu;
    const float rstd = rsqrtf(var + 1e-6f);
#pragma unroll
    for (int i = 0; i < 16; ++i) {
        const int c = lane + i * 64;
        const float o = (v[i] - mu) * rstd * pw[c] + pb[c];
        const ushort_t h = f2bf(o);
        hi[(size_t)row * 1024 + c] = h;
        lo[(size_t)row * 1024 + c] = f2bf(o - bf2f(h));
    }
}

// ---------------------------------------------------------------------------
// 5. Output GEMM: same skeleton; plain fp32 epilogue. grid (64, 8).
// ---------------------------------------------------------------------------
__global__ __launch_bounds__(512) void out_gemm_kernel(
    const ushort_t* __restrict__ Ahg, const ushort_t* __restrict__ Alg,
    const ushort_t* __restrict__ Bhg, const ushort_t* __restrict__ Blg,
    float* __restrict__ out)
{
    const int rowbase = blockIdx.x * 128;
    const int colbase = blockIdx.y * 128;

    GEMM_TILE_BODY(Ahg, Alg, Bhg, Blg, rowbase, colbase)

#pragma unroll
    for (int t = 0; t < 4; ++t)
#pragma unroll
        for (int u = 0; u < 2; ++u) {
            const int col = colbase + wn * 32 + u * 16 + l15;
#pragma unroll
            for (int r = 0; r < 4; ++r) {
                const int row = rowbase + wm * 64 + t * 16 + lq * 4 + r;
                out[(size_t)row * 1024 + col] = acc[t][u][r];
            }
        }
}

// ---------------------------------------------------------------------------
extern "C" void kernel_launch(void* const* d_in, const int* in_sizes, int n_in,
                              void* d_out, int out_size, void* d_ws, size_t ws_size,
                              hipStream_t stream) {
    const float* x    = (const float*)d_in[0];
    const float* posf = (const float*)d_in[1];
    const float* Wq   = (const float*)d_in[2];
    const float* Wk   = (const float*)d_in[3];
    const float* Wv   = (const float*)d_in[4];
    const float* Wo   = (const float*)d_in[5];
    const float* lrW  = (const float*)d_in[6];
    const float* lrb  = (const float*)d_in[7];
    const float* gsc  = (const float*)d_in[8];
    const float* tg   = (const float*)d_in[9];
    const float* tb   = (const float*)d_in[10];
    const float* pw   = (const float*)d_in[11];
    const float* pb   = (const float*)d_in[12];
    const float* coeff= (const float*)d_in[13];
    // d_in[14] = knots: uniform linspace(-1,1,15); closed-form in scan.

    char* ws = (char*)d_ws;
    float*    Qb   = (float*)(ws);                      // 32 MB [dead after scan]
    float*    Kb   = (float*)(ws + 33554432);           // 32 MB [dead after scan]
    float*    Vb   = (float*)(ws + 67108864);           // 32 MB
    ushort_t* xh   = (ushort_t*)(ws + 100663296);       // 16 MB [dead after qkv]
    ushort_t* xl   = (ushort_t*)(ws + 117440512);       // 16 MB
    float*    outp = (float*)(ws + 100663296);          // 32 MB (aliases xh+xl)
    float*    eta  = (float*)(ws + 134217728);          // 0.5 MB
    ushort_t* Wqh  = (ushort_t*)(ws + 134742016);       // 2 MB each
    ushort_t* Wql  = (ushort_t*)(ws + 136839168);
    ushort_t* Wkh  = (ushort_t*)(ws + 138936320);
    ushort_t* Wkl  = (ushort_t*)(ws + 141033472);
    ushort_t* Wvh  = (ushort_t*)(ws + 143130624);
    ushort_t* Wvl  = (ushort_t*)(ws + 145227776);
    ushort_t* Woh  = (ushort_t*)(ws + 147324928);
    ushort_t* Wol  = (ushort_t*)(ws + 149422080);       // end 151519232
    ushort_t* lnh  = (ushort_t*)(ws);                   // aliases Qb (dead)
    ushort_t* lnl  = (ushort_t*)(ws + 16777216);

    split_kernel<<<8192, 256, 0, stream>>>(x,  xh,  xl,  2097152);
    split_kernel<<<1024, 256, 0, stream>>>(Wq, Wqh, Wql, 262144);
    split_kernel<<<1024, 256, 0, stream>>>(Wk, Wkh, Wkl, 262144);
    split_kernel<<<1024, 256, 0, stream>>>(Wv, Wvh, Wvl, 262144);
    split_kernel<<<1024, 256, 0, stream>>>(Wo, Woh, Wol, 262144);
    eta_kernel<<<2048, 256, 0, stream>>>(x, lrW, lrb, gsc, eta);
    qkv_rope_kernel<<<dim3(64, 24), 512, 0, stream>>>(xh, xl, Wqh, Wql, Wkh, Wkl,
                                                      Wvh, Wvl, posf, Qb, Kb, Vb);
    scan_kernel<<<64, 1024, 0, stream>>>(Qb, Kb, Vb, eta, tg, tb, coeff, outp);
    ln_kernel<<<2048, 256, 0, stream>>>(outp, pw, pb, lnh, lnl);
    out_gemm_kernel<<<dim3(64, 8), 512, 0, stream>>>(lnh, lnl, Woh, Wol, (float*)d_out);
}